// Round 11
// baseline (141.957 us; speedup 1.0000x reference)
//
#include <hip/hip_runtime.h>

// ---------- types ----------
typedef __bf16 bf16;
typedef __bf16 bf16x4 __attribute__((ext_vector_type(4)));
typedef __bf16 bf16x8 __attribute__((ext_vector_type(8)));
typedef float f32x4 __attribute__((ext_vector_type(4)));

#define ALPHA_ 0.125f   // 1/sqrt(64)

// H=8 heads, B=16, N=512, HID=512, D=64, M = B*N = 8192
// ws layout (bytes):
//   xb    [8192][512] bf16             @ 0          (8,388,608)
//   wcat  [1536][512] bf16 (B^T)       @ 8388608    (1,572,864)
//   wot   [512][512]  bf16 (Wo^T)      @ 9961472    (524,288)
//   Q     [8][8192][64] bf16           @ 10485760   (8,388,608)
//   K     [8][8192][64] bf16           @ 18874368   (8,388,608)
//   Vt    [8][16][64][512] bf16        @ 27262976   (8,388,608)
//   Oatt  [8192][512] bf16             @ 35651584   (8,388,608)

__device__ __forceinline__ void gload16(const void* g, void* l) {
  __builtin_amdgcn_global_load_lds((__attribute__((address_space(1))) void*)(g),
                                   (__attribute__((address_space(3))) void*)(l),
                                   16, 0, 0);
}

// pinned-issue global loads (16B) -> explicit VGPR quad destinations
#define GL128(dst, ptr) \
  asm volatile("global_load_dwordx4 %0, %1, off" : "=v"(dst) : "v"(ptr) : "memory")
// counted vmem wait + scheduler fence (rule 18)
#define VWAIT(N)                                                   \
  do {                                                             \
    asm volatile("s_waitcnt vmcnt(" #N ")" ::: "memory");          \
    __builtin_amdgcn_sched_barrier(0);                             \
  } while (0)

// ---------- prep kernels ----------
__global__ void cast_x_kernel(const float* __restrict__ x, bf16* __restrict__ xb) {
  int i = blockIdx.x * 256 + threadIdx.x;
  float4 v = ((const float4*)x)[i];
  bf16x4 o = {(bf16)v.x, (bf16)v.y, (bf16)v.z, (bf16)v.w};
  ((bf16x4*)xb)[i] = o;
}

__global__ void prep_w_kernel(const float* __restrict__ Wq, const float* __restrict__ Wk,
                              const float* __restrict__ Wv, bf16* __restrict__ wcat) {
  int i = blockIdx.x * 256 + threadIdx.x;          // 786,432 = 1536*512
  int h = i & 511, j = i >> 9;
  int qkv = j >> 9, g = (j >> 6) & 7, d = j & 63;
  const float* W = (qkv == 0) ? Wq : ((qkv == 1) ? Wk : Wv);
  wcat[i] = (bf16)W[((g << 9) + h) * 64 + d];      // wcat[j][h] = W[g][h][d]
}

__global__ void prep_wo_kernel(const float* __restrict__ Wo, bf16* __restrict__ wot) {
  int i = blockIdx.x * 256 + threadIdx.x;          // 262,144
  int k = i & 511, n = i >> 9;
  wot[i] = (bf16)Wo[(k << 9) + n];                 // wot[n][k] = Wo[k][n]
}

// ---------- GEMM: C = A[M,K] * Bt[N,K]^T, bf16 in, f32 acc ----------
// 2-phase double-buffered: stage(t+1) issued BEFORE compute(t); one
// vmcnt(0)+barrier per K-step. MODE 0: QKV scatter; MODE 1: f32 C write.
template <int RM, int RN, int MODE>
__global__ __launch_bounds__(256, 2) void gemm2_kernel(
    const bf16* __restrict__ A, const bf16* __restrict__ Bt, int Kdim, int Ndim,
    float* __restrict__ Cf, bf16* __restrict__ Qo, bf16* __restrict__ Ko,
    bf16* __restrict__ Vto) {
  constexpr int BM = RM * 64, BN = RN * 64;
  constexpr int MI = BM / 32, NJ = BN / 32;
  __shared__ bf16 lA[2][BM * 32];
  __shared__ bf16 lB[2][BN * 32];
  const int t = threadIdx.x;
  const int w = t >> 6;
  const int lane = t & 63;
  const int lhi = lane >> 4, llo = lane & 15;
  const int m0 = blockIdx.y * BM, n0 = blockIdx.x * BN;
  const int wr = (w >> 1) * (BM / 2), wc = (w & 1) * (BN / 2);

  f32x4 acc[MI][NJ] = {};
  const int nkt = Kdim >> 5;

  auto stage = [&](int buf, int kt) {
#pragma unroll
    for (int c = 0; c < RM; ++c) {
      int u = c * 256 + t;
      gload16(A + (size_t)(m0 + (u >> 2)) * Kdim + kt * 32 + (u & 3) * 8,
              &lA[buf][c * 2048 + w * 512]);
    }
#pragma unroll
    for (int c = 0; c < RN; ++c) {
      int u = c * 256 + t;
      gload16(Bt + (size_t)(n0 + (u >> 2)) * Kdim + kt * 32 + (u & 3) * 8,
              &lB[buf][c * 2048 + w * 512]);
    }
  };

  stage(0, 0);
  asm volatile("s_waitcnt vmcnt(0)" ::: "memory");
  __builtin_amdgcn_s_barrier();
  __builtin_amdgcn_sched_barrier(0);

  for (int kt = 0; kt < nkt; ++kt) {
    const int cur = kt & 1;
    if (kt + 1 < nkt) stage(cur ^ 1, kt + 1);
    __builtin_amdgcn_sched_barrier(0);

    bf16x8 af[MI], bfr[NJ];
#pragma unroll
    for (int i = 0; i < MI; ++i)
      af[i] = *(const bf16x8*)&lA[cur][(wr + i * 16 + llo) * 32 + lhi * 8];
#pragma unroll
    for (int j = 0; j < NJ; ++j)
      bfr[j] = *(const bf16x8*)&lB[cur][(wc + j * 16 + llo) * 32 + lhi * 8];
#pragma unroll
    for (int i = 0; i < MI; ++i)
#pragma unroll
      for (int j = 0; j < NJ; ++j)
        acc[i][j] = __builtin_amdgcn_mfma_f32_16x16x32_bf16(af[i], bfr[j], acc[i][j], 0, 0, 0);

    __builtin_amdgcn_sched_barrier(0);
    asm volatile("s_waitcnt vmcnt(0)" ::: "memory");
    __builtin_amdgcn_s_barrier();
    __builtin_amdgcn_sched_barrier(0);
  }

#pragma unroll
  for (int i = 0; i < MI; ++i) {
    int row = m0 + wr + i * 16 + lhi * 4;
#pragma unroll
    for (int j = 0; j < NJ; ++j) {
      int col = n0 + wc + j * 16 + llo;
#pragma unroll
      for (int r = 0; r < 4; ++r) {
        float v = acc[i][j][r];
        int rr = row + r;
        if (MODE == 0) {
          int qkv = col >> 9, g = (col >> 6) & 7, d = col & 63;
          bf16 bv = (bf16)v;
          if (qkv == 0)
            Qo[((size_t)g * 8192 + rr) * 64 + d] = bv;
          else if (qkv == 1)
            Ko[((size_t)g * 8192 + rr) * 64 + d] = bv;
          else {
            int b = rr >> 9, n = rr & 511;
            Vto[(((size_t)g * 16 + b) * 64 + d) * 512 + n] = bv;
          }
        } else {
          Cf[(size_t)rr * Ndim + col] = v;
        }
      }
    }
  }
}

// ---------- fused attention ----------
// grid (8,16,8), 256 threads = 4 INDEPENDENT waves (no block barriers).
// R10 ring for K/V (pinned GL128, counted vmcnt). EDGE PATH REWORKED:
// per 64-kv chunk, 4 pinned GL128 read 256B-CONTIGUOUS row segments
// (4 rows x 256B per instr; was 16 x 64B scatter) into regs, ds_write into
// a wave-private XOR-swizzled LDS pane; fragment ds_read_b128 replaces the
// old scattered global edge loads. LDS ops are same-wave (in-order), no
// barriers. vmcnt ring re-derived (in-order retirement), per-it constants.
__global__ __launch_bounds__(256, 4) void attn_kernel(
    const bf16* __restrict__ Qa, const bf16* __restrict__ Ka,
    const bf16* __restrict__ Vta, const float* __restrict__ edge,
    bf16* __restrict__ Oatt) {
  __shared__ f32x4 eL[4][2][256];   // per wave x 2 chunk bufs x (16 rows x 16 units)
  const int t = threadIdx.x, w = t >> 6, lane = t & 63;
  const int lhi = lane >> 4, llo = lane & 15;
  const int qt = blockIdx.x, b = blockIdx.y, g = blockIdx.z;
  const int q0 = qt * 64 + w * 16;
  const bf16* Qg = Qa + ((size_t)g * 8192 + b * 512) * 64;
  const bf16* Kg = Ka + ((size_t)g * 8192 + b * 512) * 64;
  const bf16* Vg = Vta + ((size_t)g * 16 + b) * (64 * 512);
  const float* eg = edge + ((size_t)g * 16 + b) * (512 * 512);

  // K/V per-lane stream bases (element offsets) — R10 verbatim
  const bf16* kbase = Kg + (size_t)llo * 64 + lhi * 8;
  const bf16* vbase = Vg + (size_t)llo * 512 + lhi * 8;
  // edge staging base: instr j covers rows j*4 + (lane>>4), 256B/row
  const int erow = lane >> 4;           // 0..3 within 4-row group
  const int eunit = lane & 15;          // 16B unit within row (kv/4)
  const float* ebase2 = eg + (size_t)(q0 + erow) * 512 + eunit * 4;  // + j*2048 + c*64

  // Q fragments (B-operand: col = llo = q-row), persistent
  bf16x8 qf[2];
#pragma unroll
  for (int ks = 0; ks < 2; ++ks)
    qf[ks] = *(const bf16x8*)(Qg + (size_t)(q0 + llo) * 64 + ks * 32 + lhi * 8);

  f32x4 oacc[4] = {};
  float mrow = -3e38f, lrow = 0.f;

  bf16x8 kf[2][2], vf[4];
  f32x4 er[4];

  // ---- prologue: E(chunk0) 4, K(0) 4, V(0) 4 ----
  GL128(er[0], ebase2 + 0 * 2048);
  GL128(er[1], ebase2 + 1 * 2048);
  GL128(er[2], ebase2 + 2 * 2048);
  GL128(er[3], ebase2 + 3 * 2048);
  GL128(kf[0][0], kbase + 0);
  GL128(kf[0][1], kbase + 1024);
  GL128(kf[1][0], kbase + 32);
  GL128(kf[1][1], kbase + 1024 + 32);
  GL128(vf[0], vbase + 0);
  GL128(vf[1], vbase + 8192);
  GL128(vf[2], vbase + 16384);
  GL128(vf[3], vbase + 24576);
  VWAIT(8);                         // E(0) ready (K0,V0 newer)
#pragma unroll
  for (int j = 0; j < 4; ++j) {     // ds_write chunk 0 -> buf 0 (XOR swizzle)
    int row = j * 4 + erow;
    eL[w][0][row * 16 + (eunit ^ row)] = er[j];
  }
#pragma unroll
  for (int j = 0; j < 4; ++j)       // issue E(chunk1)
    GL128(er[j], ebase2 + j * 2048 + 64);

#pragma unroll
  for (int it = 0; it < 16; ++it) {
    const int c = it >> 1, p = it & 1;
    const int kvn = (it + 1) * 32;

    // ---- waitA: K(it) ready (in-order retirement table, see analysis) ----
    if (it == 0) { VWAIT(8); }
    else if ((it & 1) == 1 && it != 1 && it != 15) { VWAIT(8); }
    else { VWAIT(4); }              // it==1, even its, it==15

    // S^T = K Q^T : sc[ni][r] = S[q=llo][kv = ni*16 + lhi*4 + r]
    f32x4 sc[2] = {};
    __builtin_amdgcn_s_setprio(1);
#pragma unroll
    for (int ks = 0; ks < 2; ++ks)
#pragma unroll
      for (int ni = 0; ni < 2; ++ni)
        sc[ni] = __builtin_amdgcn_mfma_f32_16x16x32_bf16(kf[ks][ni], qf[ks], sc[ni], 0, 0, 0);
    __builtin_amdgcn_s_setprio(0);

    // issue K(t+1)
    if (it < 15) {
      const bf16* kb = kbase + (size_t)kvn * 64;
      GL128(kf[0][0], kb + 0);
      GL128(kf[0][1], kb + 1024);
      GL128(kf[1][0], kb + 32);
      GL128(kf[1][1], kb + 1024 + 32);
    }

    // ---- edge chunk maintenance (p==0, it>=2): write chunk c, issue E(c+1) --
    if (p == 0 && it >= 2) {
#pragma unroll
      for (int j = 0; j < 4; ++j) {
        int row = j * 4 + erow;
        eL[w][c & 1][row * 16 + (eunit ^ row)] = er[j];
      }
      if (c < 7) {
#pragma unroll
        for (int j = 0; j < 4; ++j)
          GL128(er[j], ebase2 + j * 2048 + (c + 1) * 64);
      }
    }

    // ---- edge fragment from LDS (same-wave, in-order vs writes above) ----
    f32x4 ef0 = eL[w][c & 1][llo * 16 + ((p * 8 + 0 + lhi) ^ llo)];
    f32x4 ef1 = eL[w][c & 1][llo * 16 + ((p * 8 + 4 + lhi) ^ llo)];

    // ---- edge add + max ----
    float mx = -3e38f;
#pragma unroll
    for (int r = 0; r < 4; ++r) {
      float sv = fmaf(ALPHA_, sc[0][r], ef0[r]);
      sc[0][r] = sv;
      mx = fmaxf(mx, sv);
      float sv1 = fmaf(ALPHA_, sc[1][r], ef1[r]);
      sc[1][r] = sv1;
      mx = fmaxf(mx, sv1);
    }

    // ---- online softmax (reduce across lhi groups: 2 shfls each) ----
    mx = fmaxf(mx, __shfl_xor(mx, 16));
    mx = fmaxf(mx, __shfl_xor(mx, 32));
    float mnew = fmaxf(mrow, mx);
    float s = __expf(mrow - mnew);
    mrow = mnew;
    float rsum = 0.f;
#pragma unroll
    for (int ni = 0; ni < 2; ++ni)
#pragma unroll
      for (int r = 0; r < 4; ++r) {
        float pv = __expf(sc[ni][r] - mnew);
        sc[ni][r] = pv;
        rsum += pv;
      }
    rsum += __shfl_xor(rsum, 16);
    rsum += __shfl_xor(rsum, 32);
    lrow = lrow * s + rsum;

    // ---- rescale O accumulator (shfl redistribute, verbatim) ----
#pragma unroll
    for (int r = 0; r < 4; ++r) {
      float sq = __shfl(s, (lane & 48) | (lhi * 4 + r));
#pragma unroll
      for (int nc = 0; nc < 4; ++nc) oacc[nc][r] *= sq;
    }

    // ---- P A-frag via cvt_pk + permlane swaps (verbatim) ----
    bf16x8 pf;
    {
      unsigned xa, xb, ya, yb;
      asm("v_cvt_pk_bf16_f32 %0, %1, %2" : "=v"(xa) : "v"(sc[0][0]), "v"(sc[0][1]));
      asm("v_cvt_pk_bf16_f32 %0, %1, %2" : "=v"(xb) : "v"(sc[0][2]), "v"(sc[0][3]));
      asm("v_cvt_pk_bf16_f32 %0, %1, %2" : "=v"(ya) : "v"(sc[1][0]), "v"(sc[1][1]));
      asm("v_cvt_pk_bf16_f32 %0, %1, %2" : "=v"(yb) : "v"(sc[1][2]), "v"(sc[1][3]));
      asm("v_permlane32_swap_b32 %0, %1" : "+v"(xa), "+v"(ya));
      asm("v_permlane16_swap_b32 %0, %1" : "+v"(xa), "+v"(ya));
      asm("v_permlane32_swap_b32 %0, %1" : "+v"(xb), "+v"(yb));
      asm("v_permlane16_swap_b32 %0, %1" : "+v"(xb), "+v"(yb));
      union { unsigned wd[4]; bf16x8 v; } fu;
      fu.wd[0] = xa; fu.wd[1] = xb; fu.wd[2] = ya; fu.wd[3] = yb;
      pf = fu.v;
    }

    // ---- waitB: V(it) ready ----
    if (it == 15) { VWAIT(0); }
    else if (it == 0) { VWAIT(8); }
    else if ((it & 1) == 0 && it <= 12) { VWAIT(8); }
    else { VWAIT(4); }              // odd 1..13, it==14

    __builtin_amdgcn_s_setprio(1);
#pragma unroll
    for (int nc = 0; nc < 4; ++nc)
      oacc[nc] = __builtin_amdgcn_mfma_f32_16x16x32_bf16(pf, vf[nc], oacc[nc], 0, 0, 0);
    __builtin_amdgcn_s_setprio(0);

    // issue V(t+1)
    if (it < 15) {
      GL128(vf[0], vbase + kvn);
      GL128(vf[1], vbase + 8192 + kvn);
      GL128(vf[2], vbase + 16384 + kvn);
      GL128(vf[3], vbase + 24576 + kvn);
    }
  }

  // ---- normalize + write Oatt (verbatim epilogue) ----
  float rcpl = 1.0f / lrow;
#pragma unroll
  for (int r = 0; r < 4; ++r) {
    float lr = __shfl(rcpl, (lane & 48) | (lhi * 4 + r));
    int qrow = q0 + lhi * 4 + r;
#pragma unroll
    for (int nc = 0; nc < 4; ++nc) {
      float ov = oacc[nc][r] * lr;
      Oatt[((size_t)b * 512 + qrow) * 512 + g * 64 + nc * 16 + llo] = (bf16)ov;
    }
  }
}

// ---------- launch ----------
extern "C" void kernel_launch(void* const* d_in, const int* in_sizes, int n_in,
                              void* d_out, int out_size, void* d_ws, size_t ws_size,
                              hipStream_t stream) {
  (void)in_sizes; (void)n_in; (void)out_size; (void)ws_size;
  const float* x = (const float*)d_in[0];
  const float* edge = (const float*)d_in[1];
  const float* Wq = (const float*)d_in[2];
  const float* Wk = (const float*)d_in[3];
  const float* Wv = (const float*)d_in[4];
  const float* Wo = (const float*)d_in[5];
  float* out = (float*)d_out;

  char* ws = (char*)d_ws;
  bf16* xb   = (bf16*)(ws + 0);
  bf16* wcat = (bf16*)(ws + 8388608);
  bf16* wot  = (bf16*)(ws + 9961472);
  bf16* Qa   = (bf16*)(ws + 10485760);
  bf16* Ka   = (bf16*)(ws + 18874368);
  bf16* Vta  = (bf16*)(ws + 27262976);
  bf16* Oatt = (bf16*)(ws + 35651584);

  cast_x_kernel<<<4096, 256, 0, stream>>>(x, xb);
  prep_w_kernel<<<3072, 256, 0, stream>>>(Wq, Wk, Wv, wcat);
  prep_wo_kernel<<<1024, 256, 0, stream>>>(Wo, wot);

  // QKV: A=xb [8192,512], Bt=wcat [1536,512], tile 128x128
  gemm2_kernel<2, 2, 0><<<dim3(12, 64), 256, 0, stream>>>(xb, wcat, 512, 1536,
                                                          nullptr, Qa, Ka, Vta);
  // fused attention (barrier-free; contiguous edge staging via wave-private LDS)
  attn_kernel<<<dim3(8, 16, 8), 256, 0, stream>>>(Qa, Ka, Vta, edge, Oatt);
  // output projection: A=Oatt [8192,512], Bt=wot [512,512], tile 128x64 -> f32
  gemm2_kernel<2, 1, 1><<<dim3(8, 64), 256, 0, stream>>>(Oatt, wot, 512, 512,
                                                         out, nullptr, nullptr, nullptr);
}

// Round 13
// 122.950 us; speedup vs baseline: 1.1546x; 1.1546x over previous
//
#include <hip/hip_runtime.h>

// ---------- types ----------
typedef __bf16 bf16;
typedef __bf16 bf16x4 __attribute__((ext_vector_type(4)));
typedef __bf16 bf16x8 __attribute__((ext_vector_type(8)));
typedef float f32x4 __attribute__((ext_vector_type(4)));

#define ALPHA_ 0.125f   // 1/sqrt(64)

// H=8 heads, B=16, N=512, HID=512, D=64, M = B*N = 8192
// ws layout (bytes):
//   xb    [8192][512] bf16             @ 0          (8,388,608)
//   wcat  [1536][512] bf16 (B^T)       @ 8388608    (1,572,864)
//   wot   [512][512]  bf16 (Wo^T)      @ 9961472    (524,288)
//   Q     [8][8192][64] bf16           @ 10485760   (8,388,608)
//   K     [8][8192][64] bf16           @ 18874368   (8,388,608)
//   Vt    [8][16][64][512] bf16        @ 27262976   (8,388,608)
//   Oatt  [8192][512] bf16             @ 35651584   (8,388,608)

__device__ __forceinline__ void gload16(const void* g, void* l) {
  __builtin_amdgcn_global_load_lds((__attribute__((address_space(1))) void*)(g),
                                   (__attribute__((address_space(3))) void*)(l),
                                   16, 0, 0);
}

// ---------- prep kernels ----------
__global__ void cast_x_kernel(const float* __restrict__ x, bf16* __restrict__ xb) {
  int i = blockIdx.x * 256 + threadIdx.x;
  float4 v = ((const float4*)x)[i];
  bf16x4 o = {(bf16)v.x, (bf16)v.y, (bf16)v.z, (bf16)v.w};
  ((bf16x4*)xb)[i] = o;
}

__global__ void prep_w_kernel(const float* __restrict__ Wq, const float* __restrict__ Wk,
                              const float* __restrict__ Wv, bf16* __restrict__ wcat) {
  int i = blockIdx.x * 256 + threadIdx.x;          // 786,432 = 1536*512
  int h = i & 511, j = i >> 9;
  int qkv = j >> 9, g = (j >> 6) & 7, d = j & 63;
  const float* W = (qkv == 0) ? Wq : ((qkv == 1) ? Wk : Wv);
  wcat[i] = (bf16)W[((g << 9) + h) * 64 + d];      // wcat[j][h] = W[g][h][d]
}

__global__ void prep_wo_kernel(const float* __restrict__ Wo, bf16* __restrict__ wot) {
  int i = blockIdx.x * 256 + threadIdx.x;          // 262,144
  int k = i & 511, n = i >> 9;
  wot[i] = (bf16)Wo[(k << 9) + n];                 // wot[n][k] = Wo[k][n]
}

// ---------- GEMM: C = A[M,K] * Bt[N,K]^T, bf16 in, f32 acc (R8 verbatim) ----------
template <int RM, int RN, int MODE>
__global__ __launch_bounds__(256, 2) void gemm2_kernel(
    const bf16* __restrict__ A, const bf16* __restrict__ Bt, int Kdim, int Ndim,
    float* __restrict__ Cf, bf16* __restrict__ Qo, bf16* __restrict__ Ko,
    bf16* __restrict__ Vto) {
  constexpr int BM = RM * 64, BN = RN * 64;
  constexpr int MI = BM / 32, NJ = BN / 32;
  __shared__ bf16 lA[2][BM * 32];
  __shared__ bf16 lB[2][BN * 32];
  const int t = threadIdx.x;
  const int w = t >> 6;
  const int lane = t & 63;
  const int lhi = lane >> 4, llo = lane & 15;
  const int m0 = blockIdx.y * BM, n0 = blockIdx.x * BN;
  const int wr = (w >> 1) * (BM / 2), wc = (w & 1) * (BN / 2);

  f32x4 acc[MI][NJ] = {};
  const int nkt = Kdim >> 5;

  auto stage = [&](int buf, int kt) {
#pragma unroll
    for (int c = 0; c < RM; ++c) {
      int u = c * 256 + t;
      gload16(A + (size_t)(m0 + (u >> 2)) * Kdim + kt * 32 + (u & 3) * 8,
              &lA[buf][c * 2048 + w * 512]);
    }
#pragma unroll
    for (int c = 0; c < RN; ++c) {
      int u = c * 256 + t;
      gload16(Bt + (size_t)(n0 + (u >> 2)) * Kdim + kt * 32 + (u & 3) * 8,
              &lB[buf][c * 2048 + w * 512]);
    }
  };

  stage(0, 0);
  asm volatile("s_waitcnt vmcnt(0)" ::: "memory");
  __builtin_amdgcn_s_barrier();
  __builtin_amdgcn_sched_barrier(0);

  for (int kt = 0; kt < nkt; ++kt) {
    const int cur = kt & 1;
    if (kt + 1 < nkt) stage(cur ^ 1, kt + 1);
    __builtin_amdgcn_sched_barrier(0);

    bf16x8 af[MI], bfr[NJ];
#pragma unroll
    for (int i = 0; i < MI; ++i)
      af[i] = *(const bf16x8*)&lA[cur][(wr + i * 16 + llo) * 32 + lhi * 8];
#pragma unroll
    for (int j = 0; j < NJ; ++j)
      bfr[j] = *(const bf16x8*)&lB[cur][(wc + j * 16 + llo) * 32 + lhi * 8];
#pragma unroll
    for (int i = 0; i < MI; ++i)
#pragma unroll
      for (int j = 0; j < NJ; ++j)
        acc[i][j] = __builtin_amdgcn_mfma_f32_16x16x32_bf16(af[i], bfr[j], acc[i][j], 0, 0, 0);

    __builtin_amdgcn_sched_barrier(0);
    asm volatile("s_waitcnt vmcnt(0)" ::: "memory");
    __builtin_amdgcn_s_barrier();
    __builtin_amdgcn_sched_barrier(0);
  }

#pragma unroll
  for (int i = 0; i < MI; ++i) {
    int row = m0 + wr + i * 16 + lhi * 4;
#pragma unroll
    for (int j = 0; j < NJ; ++j) {
      int col = n0 + wc + j * 16 + llo;
#pragma unroll
      for (int r = 0; r < 4; ++r) {
        float v = acc[i][j][r];
        int rr = row + r;
        if (MODE == 0) {
          int qkv = col >> 9, g = (col >> 6) & 7, d = col & 63;
          bf16 bv = (bf16)v;
          if (qkv == 0)
            Qo[((size_t)g * 8192 + rr) * 64 + d] = bv;
          else if (qkv == 1)
            Ko[((size_t)g * 8192 + rr) * 64 + d] = bv;
          else {
            int b = rr >> 9, n = rr & 511;
            Vto[(((size_t)g * 16 + b) * 64 + d) * 512 + n] = bv;
          }
        } else {
          Cf[(size_t)rr * Ndim + col] = v;
        }
      }
    }
  }
}

// ---------- fused attention ----------
// grid (8 qtiles, 16 batch, 8 heads), 256 threads (4 waves x 16 q-rows).
// R4 structure, KVBLK=32 for occupancy: LDS 16KB (lK dbuf 2x4KB XOR(row&7),
// lV dbuf 2x4KB XOR(row&3)), eb[2][2] parity edge regs, counted vmcnt(4),
// 2 barriers/iter, 16 fully-unrolled iterations. launch_bounds(256,6) ->
// target ~80 VGPR, 6 blocks = 24 waves/CU (was 4 blocks/16 waves).
// No inline-asm loads (spill-safe). Softmax/PV lifted from passing R9 path.
__global__ __launch_bounds__(256, 6) void attn_kernel(
    const bf16* __restrict__ Qa, const bf16* __restrict__ Ka,
    const bf16* __restrict__ Vta, const float* __restrict__ edge,
    bf16* __restrict__ Oatt) {
  __shared__ bf16 lK[2][32 * 64];
  __shared__ bf16 lV[2][64 * 32];
  const int t = threadIdx.x, w = t >> 6, lane = t & 63;
  const int lhi = lane >> 4, llo = lane & 15;
  const int qt = blockIdx.x, b = blockIdx.y, g = blockIdx.z;
  const int q0 = qt * 64 + w * 16;
  const bf16* Qg = Qa + ((size_t)g * 8192 + b * 512) * 64;
  const bf16* Kg = Ka + ((size_t)g * 8192 + b * 512) * 64;
  const bf16* Vg = Vta + ((size_t)g * 16 + b) * (64 * 512);
  const float* eg = edge + ((size_t)g * 16 + b) * (512 * 512);

  // Q fragments (B-operand: col = llo = q-row), persistent
  bf16x8 qf[2];
#pragma unroll
  for (int ks = 0; ks < 2; ++ks)
    qf[ks] = *(const bf16x8*)(Qg + (size_t)(q0 + llo) * 64 + ks * 32 + lhi * 8);

  f32x4 oacc[4] = {};
  float mrow = -3e38f, lrow = 0.f;

  // staging coords (1 gload_lds chunk each for K and V per thread):
  // K tile [32 kv][64 d]: thread t -> row kr=t>>3, src col pre-swizzled
  const int kr = t >> 3;
  const int kcs = (((t & 7) ^ (kr & 7)) << 3);
  // V tile [64 d][32 kv]: thread t -> row vr=t>>2, src col pre-swizzled
  const int vr = t >> 2;
  const int vcs = (((t & 3) ^ (vr & 3)) << 3);
  // edge: row q0+llo, col kv0 + ni*16 + lhi*4
  const float* ebase = eg + (size_t)(q0 + llo) * 512 + lhi * 4;

  f32x4 eb[2][2];   // parity-indexed edge regs (static after full unroll)

  // ---- prologue: tile 0 (2 gload_lds + 2 edge loads) ----
  gload16(Kg + (size_t)kr * 64 + kcs, &lK[0][w * 512]);
  gload16(Vg + (size_t)vr * 512 + vcs, &lV[0][w * 512]);
#pragma unroll
  for (int ni = 0; ni < 2; ++ni)
    eb[0][ni] = *(const f32x4*)(ebase + ni * 16);
  __builtin_amdgcn_sched_barrier(0);

#pragma unroll
  for (int it = 0; it < 16; ++it) {
    const int cur = it & 1, nxt = cur ^ 1;

    // ---- issue tile t+1 loads (stay in flight through both barriers) ----
    if (it < 15) {
      const int kvn = (it + 1) * 32;
      gload16(Kg + (size_t)(kvn + kr) * 64 + kcs, &lK[nxt][w * 512]);
      gload16(Vg + (size_t)vr * 512 + kvn + vcs, &lV[nxt][w * 512]);
#pragma unroll
      for (int ni = 0; ni < 2; ++ni)
        eb[nxt][ni] = *(const f32x4*)(ebase + kvn + ni * 16);
    }
    __builtin_amdgcn_sched_barrier(0);
    if (it < 15)
      asm volatile("s_waitcnt vmcnt(4)" ::: "memory");
    else
      asm volatile("s_waitcnt vmcnt(0)" ::: "memory");
    __builtin_amdgcn_sched_barrier(0);
    __builtin_amdgcn_s_barrier();
    __builtin_amdgcn_sched_barrier(0);

    // ---- S^T = K Q^T : sc[ni][r] = S[q=llo][kv = ni*16 + lhi*4 + r] ----
    f32x4 sc[2] = {};
    __builtin_amdgcn_s_setprio(1);
#pragma unroll
    for (int ks = 0; ks < 2; ++ks) {
      bf16x8 kf[2];
#pragma unroll
      for (int ni = 0; ni < 2; ++ni) {
        int row = ni * 16 + llo;
        kf[ni] = *(const bf16x8*)&lK[cur][(row * 64 + ks * 32 + lhi * 8) ^ ((row & 7) << 3)];
      }
#pragma unroll
      for (int ni = 0; ni < 2; ++ni)
        sc[ni] = __builtin_amdgcn_mfma_f32_16x16x32_bf16(kf[ni], qf[ks], sc[ni], 0, 0, 0);
    }
    __builtin_amdgcn_s_setprio(0);

    // ---- edge add + online softmax (reduce over lhi: 2 shfls) ----
    float mx = -3e38f;
#pragma unroll
    for (int ni = 0; ni < 2; ++ni)
#pragma unroll
      for (int r = 0; r < 4; ++r) {
        float sv = fmaf(ALPHA_, sc[ni][r], eb[cur][ni][r]);
        sc[ni][r] = sv;
        mx = fmaxf(mx, sv);
      }
    mx = fmaxf(mx, __shfl_xor(mx, 16));
    mx = fmaxf(mx, __shfl_xor(mx, 32));
    float mnew = fmaxf(mrow, mx);
    float sfac = __expf(mrow - mnew);
    mrow = mnew;
    float rsum = 0.f;
#pragma unroll
    for (int ni = 0; ni < 2; ++ni)
#pragma unroll
      for (int r = 0; r < 4; ++r) {
        float p = __expf(sc[ni][r] - mnew);
        sc[ni][r] = p;
        rsum += p;
      }
    rsum += __shfl_xor(rsum, 16);
    rsum += __shfl_xor(rsum, 32);
    lrow = lrow * sfac + rsum;

    // ---- rescale O accumulator (shfl redistribute, verbatim) ----
#pragma unroll
    for (int r = 0; r < 4; ++r) {
      float sq = __shfl(sfac, (lane & 48) | (lhi * 4 + r));
#pragma unroll
      for (int nc = 0; nc < 4; ++nc) oacc[nc][r] *= sq;
    }

    // ---- P A-frag via cvt_pk + permlane swaps (R9-verified); O += P V ----
    __builtin_amdgcn_s_setprio(1);
    {
      unsigned xa, xb, ya, yb;
      asm("v_cvt_pk_bf16_f32 %0, %1, %2" : "=v"(xa) : "v"(sc[0][0]), "v"(sc[0][1]));
      asm("v_cvt_pk_bf16_f32 %0, %1, %2" : "=v"(xb) : "v"(sc[0][2]), "v"(sc[0][3]));
      asm("v_cvt_pk_bf16_f32 %0, %1, %2" : "=v"(ya) : "v"(sc[1][0]), "v"(sc[1][1]));
      asm("v_cvt_pk_bf16_f32 %0, %1, %2" : "=v"(yb) : "v"(sc[1][2]), "v"(sc[1][3]));
      asm("v_permlane32_swap_b32 %0, %1" : "+v"(xa), "+v"(ya));
      asm("v_permlane16_swap_b32 %0, %1" : "+v"(xa), "+v"(ya));
      asm("v_permlane32_swap_b32 %0, %1" : "+v"(xb), "+v"(yb));
      asm("v_permlane16_swap_b32 %0, %1" : "+v"(xb), "+v"(yb));
      union { unsigned wd[4]; bf16x8 v; } fu;
      fu.wd[0] = xa; fu.wd[1] = xb; fu.wd[2] = ya; fu.wd[3] = yb;
      bf16x8 pf = fu.v;

      bf16x8 vf[4];
#pragma unroll
      for (int nc = 0; nc < 4; ++nc) {
        int row = nc * 16 + llo;
        vf[nc] = *(const bf16x8*)&lV[cur][(row * 32 + lhi * 8) ^ ((row & 3) << 3)];
      }
#pragma unroll
      for (int nc = 0; nc < 4; ++nc)
        oacc[nc] = __builtin_amdgcn_mfma_f32_16x16x32_bf16(pf, vf[nc], oacc[nc], 0, 0, 0);
    }
    __builtin_amdgcn_s_setprio(0);

    if (it < 15) {
      // barrier B: all waves done reading buf[cur] before next iter's
      // gload_lds (issued after this point) overwrites it
      __builtin_amdgcn_sched_barrier(0);
      __builtin_amdgcn_s_barrier();
      __builtin_amdgcn_sched_barrier(0);
    }
  }

  // ---- normalize + write Oatt [b*512+q][g*64+d] (verbatim epilogue) ----
  float rcpl = 1.0f / lrow;
#pragma unroll
  for (int r = 0; r < 4; ++r) {
    float lr = __shfl(rcpl, (lane & 48) | (lhi * 4 + r));
    int qrow = q0 + lhi * 4 + r;
#pragma unroll
    for (int nc = 0; nc < 4; ++nc) {
      float ov = oacc[nc][r] * lr;
      Oatt[((size_t)b * 512 + qrow) * 512 + g * 64 + nc * 16 + llo] = (bf16)ov;
    }
  }
}

// ---------- launch ----------
extern "C" void kernel_launch(void* const* d_in, const int* in_sizes, int n_in,
                              void* d_out, int out_size, void* d_ws, size_t ws_size,
                              hipStream_t stream) {
  (void)in_sizes; (void)n_in; (void)out_size; (void)ws_size;
  const float* x = (const float*)d_in[0];
  const float* edge = (const float*)d_in[1];
  const float* Wq = (const float*)d_in[2];
  const float* Wk = (const float*)d_in[3];
  const float* Wv = (const float*)d_in[4];
  const float* Wo = (const float*)d_in[5];
  float* out = (float*)d_out;

  char* ws = (char*)d_ws;
  bf16* xb   = (bf16*)(ws + 0);
  bf16* wcat = (bf16*)(ws + 8388608);
  bf16* wot  = (bf16*)(ws + 9961472);
  bf16* Qa   = (bf16*)(ws + 10485760);
  bf16* Ka   = (bf16*)(ws + 18874368);
  bf16* Vta  = (bf16*)(ws + 27262976);
  bf16* Oatt = (bf16*)(ws + 35651584);

  cast_x_kernel<<<4096, 256, 0, stream>>>(x, xb);
  prep_w_kernel<<<3072, 256, 0, stream>>>(Wq, Wk, Wv, wcat);
  prep_wo_kernel<<<1024, 256, 0, stream>>>(Wo, wot);

  // QKV: A=xb [8192,512], Bt=wcat [1536,512], tile 128x128
  gemm2_kernel<2, 2, 0><<<dim3(12, 64), 256, 0, stream>>>(xb, wcat, 512, 1536,
                                                          nullptr, Qa, Ka, Vta);
  // fused attention (KVBLK=32, 6 blocks/CU target)
  attn_kernel<<<dim3(8, 16, 8), 256, 0, stream>>>(Qa, Ka, Vta, edge, Oatt);
  // output projection: A=Oatt [8192,512], Bt=wot [512,512], tile 128x64 -> f32
  gemm2_kernel<2, 1, 1><<<dim3(8, 64), 256, 0, stream>>>(Oatt, wot, 512, 512,
                                                         out, nullptr, nullptr, nullptr);
}